// Round 2
// baseline (976.334 us; speedup 1.0000x reference)
//
#include <hip/hip_runtime.h>

#define LENSZ 11
#define RAD   5
#define TSX   64            // tile width  (4 px per thread in x)
#define TSY   16            // tile height
#define WINX  (TSX + LENSZ - 1)   // 74
#define WINY  (TSY + LENSZ - 1)   // 26
#define NI    19            // ceil(WINX/4)
#define WXP   76            // padded window width for staging (4*NI)
#define IMG_H 1024
#define IMG_W 1024
#define HW    (IMG_H * IMG_W)

// sigmoid(4*(sd-dd)) = 1/(1 + exp2(C4L2*(sd-dd))), C4L2 = -4*log2(e)
#define C4L2  (-5.770780163555854f)

__global__ __launch_bounds__(256) void scatter_render_kernel(
    const float* __restrict__ x,      // (B,4,H,W)
    const float* __restrict__ lens,   // (B,1)
    float* __restrict__ out)          // (B,3,H,W)
{
    // column-mod-4 interleaved window: win4[c&3][wy][c>>2]
    __shared__ float4 win4[4][WINY][NI];

    const int b   = blockIdx.z;
    const int bx0 = blockIdx.x * TSX;
    const int by0 = blockIdx.y * TSY;
    const int tx  = threadIdx.x;      // 0..15
    const int ty  = threadIdx.y;      // 0..15
    const int tid = ty * 16 + tx;

    const float scale = lens[b];
    const float* xb = x + (size_t)b * 4 * HW;

    // ---- stage window: iterate (wy, c) so global reads are coalesced and
    // LDS writes spread across banks (8 consecutive c cover all 32 banks).
    for (int idx = tid; idx < WINY * WXP; idx += 256) {
        int wy = idx / WXP;
        int c  = idx - wy * WXP;
        int cc = min(c, WINX - 1);               // clamp padding columns
        int gy = by0 - RAD + wy; gy = min(max(gy, 0), IMG_H - 1);
        int gx = bx0 - RAD + cc; gx = min(max(gx, 0), IMG_W - 1);
        int base = gy * IMG_W + gx;
        float4 v;
        v.x = xb[base];
        v.y = xb[base + HW];
        v.z = xb[base + 2 * HW];
        v.w = xb[base + 3 * HW];
        win4[c & 3][wy][c >> 2] = v;
    }
    __syncthreads();

    // per-dest occlusion gate precompute: G_j = exp2(-C4L2 * dd_j)
    float G[4];
#pragma unroll
    for (int j = 0; j < 4; ++j) {
        const int cc = j + RAD;                  // center column = 4tx + j + RAD
        float dd = win4[cc & 3][ty + RAD][tx + (cc >> 2)].w;
        G[j] = __builtin_amdgcn_exp2f(-C4L2 * dd);
    }

    float nr[4] = {0.f, 0.f, 0.f, 0.f};
    float ng[4] = {0.f, 0.f, 0.f, 0.f};
    float nb[4] = {0.f, 0.f, 0.f, 0.f};
    float dn[4] = {0.f, 0.f, 0.f, 0.f};

    // active dx range per disk row (dist <= 5.5)
    constexpr int XMIN[LENSZ] = {3, 2, 1, 0, 0, 0, 0, 0, 1, 2, 3};
    constexpr int XMAX[LENSZ] = {7, 8, 9, 10, 10, 10, 10, 10, 9, 8, 7};

#pragma unroll
    for (int ky = 0; ky < LENSZ; ++ky) {
#pragma unroll
        for (int kxp = XMIN[ky]; kxp <= XMAX[ky] + 3; ++kxp) {
            // source column c = 4*tx + kxp  (kxp < 16, no carry into c>>2)
            float4 s = win4[kxp & 3][ty + ky][tx + (kxp >> 2)];
            const float sd  = s.w;
            const float coc = scale * fabsf(sd);                    // source-only
            const float Es  = __builtin_amdgcn_exp2f(C4L2 * sd);    // source-only
#pragma unroll
            for (int j = 0; j < 4; ++j) {
                const int kx = kxp - j;
                if (kx < XMIN[ky] || kx > XMAX[ky]) continue;       // compile-time
                const int dy = ky - RAD, dx = kx - RAD;
                const float c0 = 0.5f - sqrtf((float)(dy * dy + dx * dx));
                float w0  = fminf(fmaxf(coc + c0, 0.f), 1.f);       // v_med3
                float f   = fmaf(Es, G[j], 1.0f);
                float occ = __builtin_amdgcn_rcpf(f);               // sigmoid
                float w   = w0 * occ;
                nr[j] = fmaf(w, s.x, nr[j]);
                ng[j] = fmaf(w, s.y, ng[j]);
                nb[j] = fmaf(w, s.z, nb[j]);
                dn[j] += w;
            }
        }
    }

    // epilogue: 4 consecutive pixels -> float4 stores per channel
    const int ox = bx0 + 4 * tx;
    const int oy = by0 + ty;
    const size_t obase = (size_t)b * 3 * HW + (size_t)oy * IMG_W + ox;

    float inv[4];
#pragma unroll
    for (int j = 0; j < 4; ++j)
        inv[j] = __builtin_amdgcn_rcpf(dn[j] + 1e-8f);

    float4 o;
    o.x = nr[0] * inv[0]; o.y = nr[1] * inv[1]; o.z = nr[2] * inv[2]; o.w = nr[3] * inv[3];
    *reinterpret_cast<float4*>(&out[obase]) = o;
    o.x = ng[0] * inv[0]; o.y = ng[1] * inv[1]; o.z = ng[2] * inv[2]; o.w = ng[3] * inv[3];
    *reinterpret_cast<float4*>(&out[obase + HW]) = o;
    o.x = nb[0] * inv[0]; o.y = nb[1] * inv[1]; o.z = nb[2] * inv[2]; o.w = nb[3] * inv[3];
    *reinterpret_cast<float4*>(&out[obase + 2 * HW]) = o;
}

extern "C" void kernel_launch(void* const* d_in, const int* in_sizes, int n_in,
                              void* d_out, int out_size, void* d_ws, size_t ws_size,
                              hipStream_t stream) {
    const float* x    = (const float*)d_in[0];
    const float* lens = (const float*)d_in[1];
    float* out        = (float*)d_out;

    const int B = in_sizes[1];  // lens_effects has B elements

    dim3 block(16, 16, 1);
    dim3 grid(IMG_W / TSX, IMG_H / TSY, B);
    scatter_render_kernel<<<grid, block, 0, stream>>>(x, lens, out);
}

// Round 3
// 116.064 us; speedup vs baseline: 8.4120x; 8.4120x over previous
//
#include <hip/hip_runtime.h>

#define LENSZ 11
#define RAD   5
#define TSX   64            // tile width  (4 px per thread in x)
#define TSY   16            // tile height
#define WINX  (TSX + LENSZ - 1)   // 74
#define WINY  (TSY + LENSZ - 1)   // 26
#define NI    19            // ceil(WINX/4)
#define WXP   76            // padded window width for staging (4*NI)
#define IMG_H 1024
#define IMG_W 1024
#define HW    (IMG_H * IMG_W)

// sigmoid(4*(sd-dd)) = 1/(1 + exp2(C4L2*(sd-dd))), C4L2 = -4*log2(e)
#define C4L2  (-5.770780163555854f)

// Process one window row `KY_` (runtime) with compile-time disk bounds
// [XMN, XMX]. kxp = source column offset; dest j uses kx = kxp - j.
#define ROWBODY(KY_, XMN, XMX)                                              \
  {                                                                          \
    const int ky_ = (KY_);                                                   \
    const float dyf_ = (float)(ky_ - RAD);                                   \
    const float dy2_ = dyf_ * dyf_;                                          \
    float c0r[LENSZ];                                                        \
    _Pragma("unroll")                                                        \
    for (int kx = (XMN); kx <= (XMX); ++kx) {                                \
      const float dxf = (float)(kx - RAD);                                   \
      c0r[kx] = 0.5f - __builtin_amdgcn_sqrtf(dy2_ + dxf * dxf);             \
    }                                                                        \
    _Pragma("unroll")                                                        \
    for (int kxp = (XMN); kxp <= (XMX) + 3; ++kxp) {                         \
      float4 s = win4[kxp & 3][ty + ky_][tx + (kxp >> 2)];                   \
      const float sd  = s.w;                                                 \
      const float coc = scale * fabsf(sd);                                   \
      const float Es  = __builtin_amdgcn_exp2f(C4L2 * sd);                   \
      _Pragma("unroll")                                                      \
      for (int j = 0; j < 4; ++j) {                                          \
        const int kx = kxp - j;                                              \
        if (kx < (XMN) || kx > (XMX)) continue;   /* compile-time */         \
        float w0  = fminf(fmaxf(coc + c0r[kx], 0.f), 1.f);                   \
        float occ = __builtin_amdgcn_rcpf(fmaf(Es, G[j], 1.0f));             \
        float w   = w0 * occ;                                                \
        nr[j] = fmaf(w, s.x, nr[j]);                                         \
        ng[j] = fmaf(w, s.y, ng[j]);                                         \
        nb[j] = fmaf(w, s.z, nb[j]);                                         \
        dn[j] += w;                                                          \
      }                                                                      \
    }                                                                        \
  }

__global__ __launch_bounds__(256) void scatter_render_kernel(
    const float* __restrict__ x,      // (B,4,H,W)
    const float* __restrict__ lens,   // (B,1)
    float* __restrict__ out)          // (B,3,H,W)
{
    // column-mod-4 interleaved window: element (wy, c) lives at win4[c&3][wy][c>>2]
    __shared__ float4 win4[4][WINY][NI];

    const int b   = blockIdx.z;
    const int bx0 = blockIdx.x * TSX;
    const int by0 = blockIdx.y * TSY;
    const int tx  = threadIdx.x;      // 0..15
    const int ty  = threadIdx.y;      // 0..15
    const int tid = ty * 16 + tx;

    const float scale = lens[b];
    const float* xb = x + (size_t)b * 4 * HW;

    // ---- stage window: coalesced global reads, bank-uniform LDS writes
    for (int idx = tid; idx < WINY * WXP; idx += 256) {
        int wy = idx / WXP;
        int c  = idx - wy * WXP;
        int cc = min(c, WINX - 1);               // clamp padding columns
        int gy = by0 - RAD + wy; gy = min(max(gy, 0), IMG_H - 1);
        int gx = bx0 - RAD + cc; gx = min(max(gx, 0), IMG_W - 1);
        int base = gy * IMG_W + gx;
        float4 v;
        v.x = xb[base];
        v.y = xb[base + HW];
        v.z = xb[base + 2 * HW];
        v.w = xb[base + 3 * HW];
        win4[c & 3][wy][c >> 2] = v;
    }
    __syncthreads();

    // per-dest occlusion gate: G_j = exp2(-C4L2 * dd_j)
    float G[4];
#pragma unroll
    for (int j = 0; j < 4; ++j) {
        const int cc = 4 * tx + j + RAD;
        float dd = win4[cc & 3][ty + RAD][cc >> 2].w;
        G[j] = __builtin_amdgcn_exp2f(-C4L2 * dd);
    }

    float nr[4] = {0.f, 0.f, 0.f, 0.f};
    float ng[4] = {0.f, 0.f, 0.f, 0.f};
    float nb[4] = {0.f, 0.f, 0.f, 0.f};
    float dn[4] = {0.f, 0.f, 0.f, 0.f};

    // disk rows grouped by identical active-x bounds; runtime ky loops keep
    // only one row's ds_reads live at a time (R1's full unroll spilled).
#pragma unroll 1
    for (int t = 0; t < 2; ++t) ROWBODY(t * 10, 3, 7)        // rows 0, 10
#pragma unroll 1
    for (int t = 0; t < 2; ++t) ROWBODY(1 + t * 8, 2, 8)     // rows 1, 9
#pragma unroll 1
    for (int t = 0; t < 2; ++t) ROWBODY(2 + t * 6, 1, 9)     // rows 2, 8
#pragma unroll 1
    for (int ky = 3; ky <= 7; ++ky) ROWBODY(ky, 0, 10)       // rows 3..7

    // epilogue: 4 consecutive pixels -> float4 stores per channel
    const int ox = bx0 + 4 * tx;
    const int oy = by0 + ty;
    const size_t obase = (size_t)b * 3 * HW + (size_t)oy * IMG_W + ox;

    float inv[4];
#pragma unroll
    for (int j = 0; j < 4; ++j)
        inv[j] = __builtin_amdgcn_rcpf(dn[j] + 1e-8f);

    float4 o;
    o.x = nr[0] * inv[0]; o.y = nr[1] * inv[1]; o.z = nr[2] * inv[2]; o.w = nr[3] * inv[3];
    *reinterpret_cast<float4*>(&out[obase]) = o;
    o.x = ng[0] * inv[0]; o.y = ng[1] * inv[1]; o.z = ng[2] * inv[2]; o.w = ng[3] * inv[3];
    *reinterpret_cast<float4*>(&out[obase + HW]) = o;
    o.x = nb[0] * inv[0]; o.y = nb[1] * inv[1]; o.z = nb[2] * inv[2]; o.w = nb[3] * inv[3];
    *reinterpret_cast<float4*>(&out[obase + 2 * HW]) = o;
}

extern "C" void kernel_launch(void* const* d_in, const int* in_sizes, int n_in,
                              void* d_out, int out_size, void* d_ws, size_t ws_size,
                              hipStream_t stream) {
    const float* x    = (const float*)d_in[0];
    const float* lens = (const float*)d_in[1];
    float* out        = (float*)d_out;

    const int B = in_sizes[1];  // lens_effects has B elements

    dim3 block(16, 16, 1);
    dim3 grid(IMG_W / TSX, IMG_H / TSY, B);
    scatter_render_kernel<<<grid, block, 0, stream>>>(x, lens, out);
}